// Round 1
// 130.037 us; speedup vs baseline: 1.0033x; 1.0033x over previous
//
#include <hip/hip_runtime.h>
#include <stdint.h>

// Problem: out[m,e,k] = sum_n A[m,n] * W[e,n,k]
// == GEMM C[8192,2048] = A[8192,1024] x B[1024,2048], B[n, e*32+k] = W[e,n,k]
//
// Round-5 structure: 256x256 tile, 8 waves (2x4), BK=64, BOTH operands through
// double-buffered LDS (128 KB). B staged in kgroup-major layout [kg][col][8]
// (conflict-free frag reads, contiguous 1KB global_load_lds chunks from BG).
// A keeps the verified XOR-swizzled row-major staging. Tile t+1's staging is
// issued at the TOP of tile t's compute into distinct __shared__ buffers; the
// only drain is the compiler's vmcnt(0) at the tile-end __syncthreads, ~640cyc
// after issue -> staging latency hidden under MFMA (T3/T4 mechanism).
// Grid 256 = 1 block/CU; XCD swizzle gives each XCD one j-slice (B L2-resident).

#define M_DIM 8192
#define N_IN  1024   // reduction dim
#define E_DIM 64
#define K_DIM 32
#define J_DIM 2048   // E*K output columns

typedef __attribute__((ext_vector_type(8))) __bf16 bf16x8;
typedef __attribute__((ext_vector_type(4))) float floatx4;

__device__ inline unsigned short f2bf(float f) {
    union { float f; unsigned u; } v; v.f = f;
    unsigned u = v.u;
    u += 0x7fff + ((u >> 16) & 1);   // round-to-nearest-even
    return (unsigned short)(u >> 16);
}

// A [8192,1024] f32 -> Ab bf16 (same row-major layout). 4 elements/thread.
__global__ __launch_bounds__(256) void convert_A(const float* __restrict__ A,
                                                 unsigned short* __restrict__ Ab) {
    size_t i = (size_t)blockIdx.x * 256 + threadIdx.x;
    const float4 v = ((const float4*)A)[i];
    ushort4 o;
    o.x = f2bf(v.x); o.y = f2bf(v.y); o.z = f2bf(v.z); o.w = f2bf(v.w);
    ((ushort4*)Ab)[i] = o;
}

// W [64][1024][32] f32 -> BG[kgroup=n>>3][j=e*32+k][t=n&7] bf16  (128 x 2048 x 8).
// B fragment for 16x16x32 MFMA: lane holds B^T[col j][k = kgroup*8 + t], t=0..7
// contiguous -> one 16B load per lane, lanes j-consecutive -> coalesced.
__global__ __launch_bounds__(256) void convert_W(const float* __restrict__ W,
                                                 unsigned short* __restrict__ BG) {
    const int t   = threadIdx.x;
    const int e   = blockIdx.y;        // 0..63
    const int n0  = blockIdx.x * 64;   // 16 slabs
    const int k   = t & 31;
    const int oct = t >> 5;            // 8 octets of n within the slab
    const float* Wp = W + ((size_t)e * N_IN + n0 + oct * 8) * K_DIM + k;
    unsigned short tmp[8];
#pragma unroll
    for (int u = 0; u < 8; ++u) tmp[u] = f2bf(Wp[(size_t)u * K_DIM]);  // coalesced per u
    unsigned short* out = BG + ((size_t)((n0 >> 3) + oct) * J_DIM + e * K_DIM + k) * 8;
    ushort4 lo, hi;
    lo.x = tmp[0]; lo.y = tmp[1]; lo.z = tmp[2]; lo.w = tmp[3];
    hi.x = tmp[4]; hi.y = tmp[5]; hi.z = tmp[6]; hi.w = tmp[7];
    ((ushort4*)out)[0] = lo;
    ((ushort4*)out)[1] = hi;           // 16B per thread, k-consecutive threads contiguous
}

__global__ __launch_bounds__(512, 2) void gemm_bt(const unsigned short* __restrict__ Ab,
                                                  const unsigned short* __restrict__ BG,
                                                  float* __restrict__ C) {
    // Four DISTINCT buffers (not [2][...]) so the compiler can prove the
    // compute-tile ds_reads never alias the in-flight staging writes.
    __shared__ unsigned short As0[16384];   // A [256 rows][8 slots][8], XOR-swizzled
    __shared__ unsigned short As1[16384];
    __shared__ unsigned short Bs0[16384];   // B [8 kg][256 cols][8], natural layout
    __shared__ unsigned short Bs1[16384];

    const int tid  = threadIdx.x;
    const int wave = tid >> 6;       // 0..7
    const int lane = tid & 63;
    const int wm = wave >> 2;        // 0..1  (M-half of 256)
    const int wn = wave & 3;         // 0..3  (N-quarter of 256)

    // XCD swizzle: dispatch d -> XCD d%8; give XCD x all blocks of j-slice x,
    // m-index advancing in dispatch order (A slabs stream in lockstep via L3).
    const int orig = blockIdx.x;            // 256 blocks = 8 j x 32 m
    const int m0 = (orig >> 3) * 256;
    const int j0 = (orig & 7) * 256;

    const int l7    = lane & 7;
    const int l15   = lane & 15;
    const int quad  = lane >> 4;     // 0..3
    const int lrow8 = lane >> 3;     // 0..7

    // --- staging addressing -------------------------------------------------
    // A: 32 chunks of 1KB (8 rows x 8 slot-groups). chunk = wave*4 + c.
    // Lane l: row_in_chunk = l>>3, LDS slot = l&7; fetches global group
    // (l&7)^(l>>3) so frag reads (group g of row r at slot g^(r&7)) work.
    const unsigned short* gA0 = Ab + (size_t)(m0 + wave * 32 + lrow8) * N_IN
                                   + ((l7 ^ lrow8) << 3);
    // B: 32 chunks of 1KB (kg = wave, 4 col-quarters). Contiguous global src.
    const unsigned short* gB0 = BG + ((size_t)wave * J_DIM + j0 + lane) * 8;
    const int stDst = wave * 2048;   // LDS dest base (shorts) for both A and B

    floatx4 acc[8][4];
#pragma unroll
    for (int i = 0; i < 8; ++i)
#pragma unroll
        for (int j = 0; j < 4; ++j) acc[i][j] = (floatx4)(0.0f);

    // --- fragment-read addressing ------------------------------------------
    const int s0    = quad ^ l7;                  // A slot for h=0 (h flips bit2)
    const int arow  = (wm * 128 + l15) * 64;      // A row base (shorts)
    const int bbase = (quad * 256 + wn * 64 + l15) * 8;   // B base (shorts)

    // --- prologue: stage tile 0 into buffer 0 -------------------------------
#pragma unroll
    for (int c = 0; c < 4; ++c)
        __builtin_amdgcn_global_load_lds(
            (const __attribute__((address_space(1))) unsigned int*)(gA0 + (size_t)c * (8 * N_IN)),
            (__attribute__((address_space(3))) unsigned int*)(As0 + stDst + c * 512),
            16, 0, 0);
#pragma unroll
    for (int c = 0; c < 4; ++c)
        __builtin_amdgcn_global_load_lds(
            (const __attribute__((address_space(1))) unsigned int*)(gB0 + c * 512),
            (__attribute__((address_space(3))) unsigned int*)(Bs0 + stDst + c * 512),
            16, 0, 0);
    __syncthreads();   // compiler emits vmcnt(0) drain here

    // --- one K-tile: issue t+1 staging first, then 64 MFMAs, then barrier ---
    auto tile = [&](int t, const unsigned short* curA, const unsigned short* curB,
                    unsigned short* nxtA, unsigned short* nxtB) {
        if (t < 15) {
            const size_t kb = (size_t)(t + 1) * 64;
#pragma unroll
            for (int c = 0; c < 4; ++c)
                __builtin_amdgcn_global_load_lds(
                    (const __attribute__((address_space(1))) unsigned int*)(gA0 + kb + (size_t)c * (8 * N_IN)),
                    (__attribute__((address_space(3))) unsigned int*)(nxtA + stDst + c * 512),
                    16, 0, 0);
#pragma unroll
            for (int c = 0; c < 4; ++c)
                __builtin_amdgcn_global_load_lds(
                    (const __attribute__((address_space(1))) unsigned int*)(gB0 + (size_t)(t + 1) * 131072 + c * 512),
                    (__attribute__((address_space(3))) unsigned int*)(nxtB + stDst + c * 512),
                    16, 0, 0);
        }
#pragma unroll
        for (int h = 0; h < 2; ++h) {
            bf16x8 bfr[4];
#pragma unroll
            for (int j = 0; j < 4; ++j)
                bfr[j] = *(const bf16x8*)(curB + h * 8192 + bbase + j * 128);
            __builtin_amdgcn_s_setprio(1);
#pragma unroll
            for (int i = 0; i < 8; ++i) {
                const bf16x8 af = *(const bf16x8*)(curA + arow + i * 1024
                                                   + ((s0 ^ (h << 2)) << 3));
#pragma unroll
                for (int j = 0; j < 4; ++j)
                    acc[i][j] = __builtin_amdgcn_mfma_f32_16x16x32_bf16(
                        af, bfr[j], acc[i][j], 0, 0, 0);
            }
            __builtin_amdgcn_s_setprio(0);
        }
        __syncthreads();   // drains next-tile staging issued ~full tile ago
    };

    for (int t = 0; t < 16; t += 2) {
        tile(t,     As0, Bs0, As1, Bs1);
        tile(t + 1, As1, Bs1, As0, Bs0);
    }

    // Epilogue: C/D layout col = lane&15, row = (lane>>4)*4 + reg
    const int crow = quad * 4;
#pragma unroll
    for (int i = 0; i < 8; ++i) {
#pragma unroll
        for (int j = 0; j < 4; ++j) {
            float* Cp = C + (size_t)(m0 + wm * 128 + i * 16 + crow) * J_DIM
                          + (j0 + wn * 64 + j * 16 + l15);
#pragma unroll
            for (int r = 0; r < 4; ++r)
                Cp[(size_t)r * J_DIM] = acc[i][j][r];
        }
    }
}

extern "C" void kernel_launch(void* const* d_in, const int* in_sizes, int n_in,
                              void* d_out, int out_size, void* d_ws, size_t ws_size,
                              hipStream_t stream) {
    const float* A = (const float*)d_in[0];   // [8192,1024]
    const float* W = (const float*)d_in[1];   // [64,1024,32]
    float* out = (float*)d_out;               // [8192,64,32] == [8192,2048]

    unsigned short* Ab = (unsigned short*)d_ws;                 // 16 MB
    unsigned short* BG = Ab + (size_t)M_DIM * N_IN;             // +4 MB

    convert_A<<<M_DIM * N_IN / (256 * 4), 256, 0, stream>>>(A, Ab);
    convert_W<<<dim3(N_IN / 64, E_DIM), 256, 0, stream>>>(W, BG);
    gemm_bt<<<dim3(256), dim3(512), 0, stream>>>(Ab, BG, out);
}